// Round 6
// baseline (326.978 us; speedup 1.0000x reference)
//
#include <hip/hip_runtime.h>
#include <math.h>

#define TT 2048   // tokens
#define Dm 1024   // model dim
#define DGc 256   // gate dim
#define Ec 8      // experts
#define Nc 9      // graph nodes
#define Hc 2048   // FFN hidden
#define PADMAX 5120
#define NTILE_MAX 40

typedef __attribute__((ext_vector_type(8))) short short8v;
typedef __attribute__((ext_vector_type(4))) float f32x4;

typedef __attribute__((address_space(1))) const void gvoid;
typedef __attribute__((address_space(3))) void svoid;

__device__ __forceinline__ void gll16(const void* g, void* l) {
    __builtin_amdgcn_global_load_lds((gvoid*)g, (svoid*)l, 16, 0, 0);
}

__device__ __forceinline__ float silu_f(float x) { return x / (1.f + __expf(-x)); }

__device__ __forceinline__ unsigned short bf16_rne(float f) {
    union { float f; unsigned u; } u; u.f = f;
    return (unsigned short)((u.u + 0x7fffu + ((u.u >> 16) & 1u)) >> 16);
}
__device__ __forceinline__ float bf16_to_f(unsigned short h) {
    union { unsigned u; float f; } u; u.u = ((unsigned)h) << 16; return u.f;
}
__device__ __forceinline__ void split2(float x, unsigned short& h, unsigned short& l) {
    h = bf16_rne(x);
    l = bf16_rne(x - bf16_to_f(h));
}

// ---- init: loss tail rows + zero expert counters + zero small accumulators ----
__global__ __launch_bounds__(256) void k_init(const float* count, const float* lamb,
        const float* theta, float* out, int* cnt, float* expg, float* Gbuf) {
    int i = threadIdx.x;
    float* loss = out + (size_t)TT * Dm;
    if (i < Ec) {
        loss[(size_t)TT * Ec + i]       = count[i];
        loss[(size_t)(TT + 1) * Ec + i] = lamb[0];
        loss[(size_t)(TT + 2) * Ec + i] = theta[0];
        cnt[i] = 0;
    }
    for (int j = i; j < Ec * DGc; j += 256) { expg[j] = 0.f; Gbuf[j] = 0.f; }
}

// ---- split hs fp32 -> hi/lo bf16 (row-major, K-contig) ----
__global__ __launch_bounds__(256) void k_split(const float* src,
        unsigned short* dh, unsigned short* dl) {
    size_t i = ((size_t)blockIdx.x * 256 + threadIdx.x) * 8;
    float4 v0 = *(const float4*)&src[i];
    float4 v1 = *(const float4*)&src[i + 4];
    ushort4 h0, l0, h1, l1;
    split2(v0.x, h0.x, l0.x); split2(v0.y, h0.y, l0.y);
    split2(v0.z, h0.z, l0.z); split2(v0.w, h0.w, l0.w);
    split2(v1.x, h1.x, l1.x); split2(v1.y, h1.y, l1.y);
    split2(v1.z, h1.z, l1.z); split2(v1.w, h1.w, l1.w);
    *(ushort4*)&dh[i] = h0; *(ushort4*)&dh[i + 4] = h1;
    *(ushort4*)&dl[i] = l0; *(ushort4*)&dl[i + 4] = l1;
}

// ---- transpose+split: src[e][R][C] f32 -> dh/dl [e][C][R] bf16 ----
__global__ __launch_bounds__(256) void k_tsplit(const float* src,
        unsigned short* dh, unsigned short* dl, int R, int C) {
    int e = blockIdx.z;
    int c0 = blockIdx.x * 32, r0 = blockIdx.y * 32;
    const float* S = src + (size_t)e * R * C;
    __shared__ float t[32][36];
    int tid = threadIdx.x;
    int i = tid >> 3, j4 = (tid & 7) * 4;
    *(float4*)&t[i][j4] = *(const float4*)&S[(size_t)(r0 + i) * C + c0 + j4];
    __syncthreads();
    int ci = tid >> 3, r4 = (tid & 7) * 4;
    ushort4 h, l;
    split2(t[r4 + 0][ci], h.x, l.x);
    split2(t[r4 + 1][ci], h.y, l.y);
    split2(t[r4 + 2][ci], h.z, l.z);
    split2(t[r4 + 3][ci], h.w, l.w);
    size_t o = (size_t)e * R * C + (size_t)(c0 + ci) * R + r0 + r4;
    *(ushort4*)&dh[o] = h;
    *(ushort4*)&dl[o] = l;
}

// ---- transpose + cast (hi only, FFN weights) ----
__global__ __launch_bounds__(256) void k_tcast(const float* src, unsigned short* dst,
                                               int R, int C) {
    int e = blockIdx.z;
    int c0 = blockIdx.x * 32, r0 = blockIdx.y * 32;
    const float* S = src + (size_t)e * R * C;
    unsigned short* Dq = dst + (size_t)e * R * C;
    __shared__ float t[32][36];
    int tid = threadIdx.x;
    int i = tid >> 3, j4 = (tid & 7) * 4;
    *(float4*)&t[i][j4] = *(const float4*)&S[(size_t)(r0 + i) * C + c0 + j4];
    __syncthreads();
    int ci = tid >> 3, r4 = (tid & 7) * 4;
    ushort4 v;
    v.x = bf16_rne(t[r4 + 0][ci]);
    v.y = bf16_rne(t[r4 + 1][ci]);
    v.z = bf16_rne(t[r4 + 2][ci]);
    v.w = bf16_rne(t[r4 + 3][ci]);
    *(ushort4*)&Dq[(size_t)(c0 + ci) * R + r0 + r4] = v;
}

// ---- expg accumulate (split-K): expg_raw[e][g] += X[e][kb:kb+64] . Wst ----
__global__ __launch_bounds__(256) void k_expgA(const float* X, const float* Wst,
                                               float* expg_raw) {
    int g = threadIdx.x;
    int kb = blockIdx.x * 64;
    __shared__ float xs[Ec][64];
    if (g < 128) {
        int e = g >> 4;
        int k4 = (g & 15) * 4;
        *(float4*)&xs[e][k4] = *(const float4*)&X[(size_t)e * Dm + kb + k4];
    }
    __syncthreads();
    float acc[Ec];
#pragma unroll
    for (int e = 0; e < Ec; e++) acc[e] = 0.f;
#pragma unroll 4
    for (int k = 0; k < 64; k++) {
        float w = Wst[(size_t)(kb + k) * DGc + g];
#pragma unroll
        for (int e = 0; e < Ec; e++) acc[e] += xs[e][k] * w;
    }
#pragma unroll
    for (int e = 0; e < Ec; e++) atomicAdd(&expg_raw[e * DGc + g], acc[e]);
}

// ---- G[m][g] += silu(expg_raw[m])[kb:kb+32] . W0 (split-K, silu folded in) ----
__global__ __launch_bounds__(256) void k_gA(const float* expg_raw, const float* W0,
                                            float* G) {
    int g = threadIdx.x;
    int kb = blockIdx.x * 32;
    __shared__ float xs[Ec][32];
    xs[g >> 5][g & 31] = silu_f(expg_raw[(size_t)(g >> 5) * DGc + kb + (g & 31)]);
    __syncthreads();
    float acc[Ec];
#pragma unroll
    for (int e = 0; e < Ec; e++) acc[e] = 0.f;
#pragma unroll 4
    for (int k = 0; k < 32; k++) {
        float w = W0[(size_t)(kb + k) * DGc + g];
#pragma unroll
        for (int e = 0; e < Ec; e++) acc[e] += xs[e][k] * w;
    }
#pragma unroll
    for (int e = 0; e < Ec; e++) atomicAdd(&G[e * DGc + g], acc[e]);
}

// ---- S1[n] = sum_{m<8} A[n,m] * G[m]  (trivial) ----
__global__ __launch_bounds__(256) void k_s1fin(const float* G, const float* Ahat,
                                               float* S1) {
    int g = threadIdx.x;
    float Gl[Ec];
#pragma unroll
    for (int m = 0; m < Ec; m++) Gl[m] = G[m * DGc + g];
#pragma unroll
    for (int n = 0; n < Nc; n++) {
        float s = 0.f;
#pragma unroll
        for (int m = 0; m < Ec; m++) s += Ahat[n * Nc + m] * Gl[m];
        S1[n * DGc + g] = s;
    }
}

// ---- split-bf16 3-pass MFMA GEMM: C[M,256] = A[M,K] @ B^T (B:[256,K]) ----
template<int BM, int KD, int EPI>
__global__ __launch_bounds__(256) void gemm4s(const unsigned short* Ah,
        const unsigned short* Al, const unsigned short* Bh, const unsigned short* Bl,
        float* Cf, unsigned short* Oh, unsigned short* Ol) {
    constexpr int FM = BM / 32;
    constexpr int AR = BM / 64;
    int m0 = blockIdx.x * BM, n0 = blockIdx.y * 128;
    __shared__ __align__(16) unsigned short AsH[BM * 32];
    __shared__ __align__(16) unsigned short AsL[BM * 32];
    __shared__ __align__(16) unsigned short BsH[128 * 32];
    __shared__ __align__(16) unsigned short BsL[128 * 32];
    int tid = threadIdx.x, lane = tid & 63, wid = tid >> 6;
    int wr = wid >> 1, wc = wid & 1, lo = lane & 15, hi = lane >> 4;

    f32x4 acc[FM][4];
#pragma unroll
    for (int m = 0; m < FM; m++)
#pragma unroll
        for (int n = 0; n < 4; n++) acc[m][n] = (f32x4)(0.f);

    int sW = (tid >> 3) & 3;
    size_t aoff = (size_t)(m0 + (tid >> 2)) * KD + ((tid & 3) ^ sW) * 8;
    size_t boff = (size_t)(n0 + (tid >> 2)) * KD + ((tid & 3) ^ sW) * 8;
    int hixor = (hi ^ ((lo >> 1) & 3)) * 8;

    for (int kb = 0; kb < KD; kb += 32) {
#pragma unroll
        for (int r = 0; r < AR; r++) {
            gll16(Ah + aoff + (size_t)r * 64 * KD + kb, (char*)AsH + r * 4096 + tid * 16);
            gll16(Al + aoff + (size_t)r * 64 * KD + kb, (char*)AsL + r * 4096 + tid * 16);
        }
#pragma unroll
        for (int r = 0; r < 2; r++) {
            gll16(Bh + boff + (size_t)r * 64 * KD + kb, (char*)BsH + r * 4096 + tid * 16);
            gll16(Bl + boff + (size_t)r * 64 * KD + kb, (char*)BsL + r * 4096 + tid * 16);
        }
        __syncthreads();
        short8v ah[FM], al[FM], bh[4], bl[4];
#pragma unroll
        for (int m = 0; m < FM; m++) {
            ah[m] = *(const short8v*)&AsH[(wr * (BM / 2) + m * 16 + lo) * 32 + hixor];
            al[m] = *(const short8v*)&AsL[(wr * (BM / 2) + m * 16 + lo) * 32 + hixor];
        }
#pragma unroll
        for (int n = 0; n < 4; n++) {
            bh[n] = *(const short8v*)&BsH[(wc * 64 + n * 16 + lo) * 32 + hixor];
            bl[n] = *(const short8v*)&BsL[(wc * 64 + n * 16 + lo) * 32 + hixor];
        }
#pragma unroll
        for (int m = 0; m < FM; m++)
#pragma unroll
            for (int n = 0; n < 4; n++)
                acc[m][n] = __builtin_amdgcn_mfma_f32_16x16x32_bf16(ah[m], bh[n], acc[m][n], 0, 0, 0);
#pragma unroll
        for (int m = 0; m < FM; m++)
#pragma unroll
            for (int n = 0; n < 4; n++)
                acc[m][n] = __builtin_amdgcn_mfma_f32_16x16x32_bf16(ah[m], bl[n], acc[m][n], 0, 0, 0);
#pragma unroll
        for (int m = 0; m < FM; m++)
#pragma unroll
            for (int n = 0; n < 4; n++)
                acc[m][n] = __builtin_amdgcn_mfma_f32_16x16x32_bf16(al[m], bh[n], acc[m][n], 0, 0, 0);
        __syncthreads();
    }

#pragma unroll
    for (int m = 0; m < FM; m++) {
#pragma unroll
        for (int n = 0; n < 4; n++) {
            int col = n0 + wc * 64 + n * 16 + lo;
#pragma unroll
            for (int r = 0; r < 4; r++) {
                int row = m0 + wr * (BM / 2) + m * 16 + hi * 4 + r;
                if (EPI == 0) {
                    Cf[(size_t)row * 256 + col] = acc[m][n][r];
                } else {
                    float s = silu_f(acc[m][n][r]);
                    unsigned short h, l;
                    split2(s, h, l);
                    Oh[(size_t)row * 256 + col] = h;
                    Ol[(size_t)row * 256 + col] = l;
                }
            }
        }
    }
}

// ---- layer-1 build: node1[t,n] = silu(S1[n] + A[n,8]*y[t]) -> hi/lo ----
__global__ __launch_bounds__(256) void k_l1(const float* y, const float* S1,
        const float* Ahat, unsigned short* nh, unsigned short* nl) {
    int t = blockIdx.x, g = threadIdx.x;
    float yv = y[(size_t)t * DGc + g];
#pragma unroll
    for (int n = 0; n < Nc; n++) {
        float c = Ahat[n * Nc + Ec];
        float s = silu_f(S1[n * DGc + g] + c * yv);
        unsigned short h, l;
        split2(s, h, l);
        size_t o = ((size_t)t * Nc + n) * DGc + g;
        nh[o] = h; nl[o] = l;
    }
}

// ---- mix: node[t,n] = silu(sum_m A[n,m] Z[t,m]) -> hi/lo ----
__global__ __launch_bounds__(256) void k_mix2(const float* Z, const float* Ahat,
        unsigned short* nh, unsigned short* nl) {
    int t = blockIdx.x, g = threadIdx.x;
    __shared__ float A[Nc * Nc];
    if (g < Nc * Nc) A[g] = Ahat[g];
    __syncthreads();
    float z[Nc];
#pragma unroll
    for (int m = 0; m < Nc; m++) z[m] = Z[((size_t)t * Nc + m) * DGc + g];
#pragma unroll
    for (int n = 0; n < Nc; n++) {
        float s = 0.f;
#pragma unroll
        for (int m = 0; m < Nc; m++) s += A[n * Nc + m] * z[m];
        s = silu_f(s);
        unsigned short h, l;
        split2(s, h, l);
        size_t o = ((size_t)t * Nc + n) * DGc + g;
        nh[o] = h; nl[o] = l;
    }
}

// ---- final mix + logits + softmax + top2 + routing (1 wave per token) ----
__global__ __launch_bounds__(256) void k_mix3(const float* Z, const float* Ahat,
        const float* wproj, float* out, int* cnt, int* toklist, float* wlist) {
    __shared__ float A[Nc * Nc];
    __shared__ float wp[DGc];
    int tid = threadIdx.x;
    if (tid < Nc * Nc) A[tid] = Ahat[tid];
    wp[tid] = wproj[tid];
    __syncthreads();
    int wid = tid >> 6, lane = tid & 63;
    int t = blockIdx.x * 4 + wid;
    float lg[Ec];
#pragma unroll
    for (int e = 0; e < Ec; e++) lg[e] = 0.f;
#pragma unroll
    for (int j = 0; j < 4; j++) {
        int g = j * 64 + lane;
        float z[Nc];
#pragma unroll
        for (int m = 0; m < Nc; m++) z[m] = Z[((size_t)t * Nc + m) * DGc + g];
#pragma unroll
        for (int e = 0; e < Ec; e++) {
            float s = 0.f;
#pragma unroll
            for (int m = 0; m < Nc; m++) s += A[e * Nc + m] * z[m];
            lg[e] += silu_f(s) * wp[g];
        }
    }
#pragma unroll
    for (int off = 32; off >= 1; off >>= 1) {
#pragma unroll
        for (int e = 0; e < Ec; e++) lg[e] += __shfl_xor(lg[e], off);
    }
    if (lane == 0) {
        float mx = -1e30f;
#pragma unroll
        for (int e = 0; e < Ec; e++) mx = fmaxf(mx, lg[e]);
        float pr[Ec], s = 0.f;
#pragma unroll
        for (int e = 0; e < Ec; e++) { pr[e] = __expf(lg[e] - mx); s += pr[e]; }
        float inv = 1.f / s;
        float* lrow = out + (size_t)TT * Dm + (size_t)t * Ec;
#pragma unroll
        for (int e = 0; e < Ec; e++) { pr[e] *= inv; lrow[e] = pr[e]; }
        int i0 = 0; float v0 = pr[0];
#pragma unroll
        for (int e = 1; e < Ec; e++) if (pr[e] > v0) { v0 = pr[e]; i0 = e; }
        int i1 = -1; float v1 = -1e30f;
#pragma unroll
        for (int e = 0; e < Ec; e++) if (e != i0 && pr[e] > v1) { v1 = pr[e]; i1 = e; }
        float* rowT = out + (size_t)TT * Dm + (size_t)TT * Ec;
        atomicAdd(&rowT[i0], 2.f * v0);
        atomicAdd(&rowT[i1], 2.f * v1);
        float winv = 1.f / (v0 + v1);
        int p0 = atomicAdd(&cnt[i0], 1);
        toklist[i0 * TT + p0] = t; wlist[i0 * TT + p0] = v0 * winv;
        int p1 = atomicAdd(&cnt[i1], 1);
        toklist[i1 * TT + p1] = t; wlist[i1 * TT + p1] = v1 * winv;
    }
}

// ---- padded offsets + tile map ----
__global__ void k_offs(const int* cnt, int* poffs, int* tile_e, int* tile_m0) {
    if (threadIdx.x == 0) {
        int pad = 0, nt = 0;
        for (int e = 0; e < Ec; e++) {
            poffs[e] = pad;
            int te = (cnt[e] + 127) >> 7;
            for (int i = 0; i < te; i++) { tile_e[nt] = e; tile_m0[nt] = pad + i * 128; nt++; }
            pad += te * 128;
        }
        poffs[Ec] = pad;
        for (; nt < NTILE_MAX; nt++) { tile_e[nt] = -1; tile_m0[nt] = 0; }
    }
}

// ---- gather routed tokens into padded slot-major bf16 buffer + slot maps ----
__global__ __launch_bounds__(256) void k_gather(const float* hs, const int* cnt,
        const int* poffs, const int* toklist, const float* wlist,
        unsigned short* xb, int* tokslot, float* wslot) {
    int tid = threadIdx.x;
    int s = blockIdx.x * 2 + (tid >> 7);
    int j = (tid & 127) * 8;
    int e = 0;
#pragma unroll
    for (int q = 1; q < Ec; q++) if (s >= poffs[q]) e = q;
    int pos = s - poffs[e];
    int tok = -1; float w = 0.f;
    if (pos < cnt[e]) { tok = toklist[e * TT + pos]; w = wlist[e * TT + pos]; }
    if (j == 0) { tokslot[s] = tok; wslot[s] = w; }
    ushort4 o0, o1;
    if (tok >= 0) {
        const float* xr = hs + (size_t)tok * Dm + j;
        o0.x = bf16_rne(xr[0]); o0.y = bf16_rne(xr[1]); o0.z = bf16_rne(xr[2]); o0.w = bf16_rne(xr[3]);
        o1.x = bf16_rne(xr[4]); o1.y = bf16_rne(xr[5]); o1.z = bf16_rne(xr[6]); o1.w = bf16_rne(xr[7]);
    } else {
        o0 = make_ushort4(0, 0, 0, 0); o1 = o0;
    }
    *(ushort4*)&xb[(size_t)s * Dm + j] = o0;
    *(ushort4*)&xb[(size_t)s * Dm + j + 4] = o1;
}

// ---- FFN MFMA grouped GEMM: 3-deep pipelined staging, counted vmcnt ----
template<int KDIM, int NDIM, int MODE>
__global__ __launch_bounds__(256) void k_mfma(const unsigned short* Abuf,
        const unsigned short* Wt, const int* tile_e, const int* tile_m0,
        const int* tokslot, const float* wslot, void* outp) {
    constexpr int NY = NDIM / 128;
    constexpr int CPX = (NTILE_MAX * NY) / 8;
    int bid = blockIdx.x;
    int flat = (bid & 7) * CPX + (bid >> 3);
    int tx = flat / NY, y = flat % NY;
    int e = tile_e[tx];
    if (e < 0) return;
    int m0 = tile_m0[tx];
    int n0 = y * 128;
    const unsigned short* Bg = Wt + (size_t)e * NDIM * KDIM;
    __shared__ __align__(16) unsigned short As[3][128 * 32];   // 24 KB
    __shared__ __align__(16) unsigned short Bs[3][128 * 32];   // 24 KB
    int tid = threadIdx.x;
    int lane = tid & 63;
    int wid = tid >> 6;
    int wr = wid >> 1, wc = wid & 1;
    int lo = lane & 15, hi = lane >> 4;

    f32x4 acc[4][4];
#pragma unroll
    for (int m = 0; m < 4; m++)
#pragma unroll
        for (int n = 0; n < 4; n++) acc[m][n] = (f32x4)(0.f);

    int arow = tid >> 2;
    int sW = (tid >> 3) & 3;
    int acol = ((tid & 3) ^ sW) * 8;           // pre-swizzled source col-block
    int hixor = (hi ^ ((lo >> 1) & 3)) * 8;    // swizzled read offset
    const unsigned short* Ag = Abuf + (size_t)m0 * KDIM;
    const unsigned short* Bt = Bg + (size_t)n0 * KDIM;

    constexpr int NT = KDIM / 32;

    // stage tile t into buffer b: 4 gll16 per thread
    #define STAGE(b, kb)                                                            \
        do {                                                                        \
            gll16(Ag + (size_t)arow * KDIM + (kb) + acol,        (char*)As[b] + tid * 16); \
            gll16(Ag + (size_t)(arow + 64) * KDIM + (kb) + acol, (char*)As[b] + 4096 + tid * 16); \
            gll16(Bt + (size_t)arow * KDIM + (kb) + acol,        (char*)Bs[b] + tid * 16); \
            gll16(Bt + (size_t)(arow + 64) * KDIM + (kb) + acol, (char*)Bs[b] + 4096 + tid * 16); \
        } while (0)

    STAGE(0, 0);
    STAGE(1, 32);

    int cur = 0;
    for (int t = 0; t < NT; t++) {
        if (t + 2 < NT) {
            int nb = cur + 2; if (nb >= 3) nb -= 3;
            STAGE(nb, (t + 2) * 32);
            asm volatile("s_waitcnt vmcnt(8)" ::: "memory");
        } else if (t + 1 < NT) {
            asm volatile("s_waitcnt vmcnt(4)" ::: "memory");
        } else {
            asm volatile("s_waitcnt vmcnt(0)" ::: "memory");
        }
        __builtin_amdgcn_s_barrier();
        short8v a[4], b[4];
#pragma unroll
        for (int m = 0; m < 4; m++)
            a[m] = *(const short8v*)&As[cur][(wr * 64 + m * 16 + lo) * 32 + hixor];
#pragma unroll
        for (int n = 0; n < 4; n++)
            b[n] = *(const short8v*)&Bs[cur][(wc * 64 + n * 16 + lo) * 32 + hixor];
#pragma unroll
        for (int m = 0; m < 4; m++)
#pragma unroll
            for (int n = 0; n < 4; n++)
                acc[m][n] = __builtin_amdgcn_mfma_f32_16x16x32_bf16(a[m], b[n], acc[m][n], 0, 0, 0);
        __builtin_amdgcn_s_barrier();
        cur = cur + 1; if (cur >= 3) cur -= 3;
    }
    #undef STAGE

    if (MODE == 0) {
        unsigned short* O = (unsigned short*)outp;
#pragma unroll
        for (int m = 0; m < 4; m++) {
#pragma unroll
            for (int n = 0; n < 4; n++) {
                int col = n0 + wc * 64 + n * 16 + lo;
#pragma unroll
                for (int r = 0; r < 4; r++) {
                    int row = m0 + wr * 64 + m * 16 + hi * 4 + r;
                    O[(size_t)row * NDIM + col] = bf16_rne(silu_f(acc[m][n][r]));
                }
            }
        }
    } else {
        float* O = (float*)outp;
#pragma unroll
        for (int m = 0; m < 4; m++) {
            int toks[4]; float ws[4];
#pragma unroll
            for (int r = 0; r < 4; r++) {
                int row = m0 + wr * 64 + m * 16 + hi * 4 + r;
                toks[r] = tokslot[row];
                ws[r] = wslot[row];
            }
#pragma unroll
            for (int n = 0; n < 4; n++) {
                int col = n0 + wc * 64 + n * 16 + lo;
#pragma unroll
                for (int r = 0; r < 4; r++) {
                    if (toks[r] >= 0)
                        atomicAdd(&O[(size_t)toks[r] * Dm + col], ws[r] * acc[m][n][r]);
                }
            }
        }
    }
}

extern "C" void kernel_launch(void* const* d_in, const int* in_sizes, int n_in,
                              void* d_out, int out_size, void* d_ws, size_t ws_size,
                              hipStream_t stream) {
    const float* hs    = (const float*)d_in[0];
    const float* X     = (const float*)d_in[1];
    const float* Wmlp  = (const float*)d_in[2];
    const float* Wst   = (const float*)d_in[3];
    const float* convW = (const float*)d_in[4];
    const float* wproj = (const float*)d_in[5];
    const float* W1    = (const float*)d_in[6];
    const float* W2    = (const float*)d_in[7];
    const float* lamb  = (const float*)d_in[8];
    const float* theta = (const float*)d_in[9];
    const float* count = (const float*)d_in[10];
    const float* Ahat  = (const float*)d_in[11];
    float* out = (float*)d_out;
    char* ws = (char*)d_ws;

    // persistent layout
    float*          expg    = (float*)ws;                       // raw accum (silu on read)
    int*            cnt     = (int*)(ws + 8192);
    int*            poffs   = (int*)(ws + 8320);
    int*            tile_e  = (int*)(ws + 8448);
    int*            tile_m0 = (int*)(ws + 8704);
    float*          S1      = (float*)(ws + 9216);
    int*            toklist = (int*)(ws + 20480);
    float*          wlist   = (float*)(ws + 86016);
    int*            tokslot = (int*)(ws + 151552);
    float*          wslot   = (float*)(ws + 172032);
    unsigned short* xb      = (unsigned short*)(ws + 196608);   // 10.5 MB
    unsigned short* W1T     = (unsigned short*)(ws + 10682368); // 33.5 MB
    unsigned short* W2T     = (unsigned short*)(ws + 44236800); // 33.5 MB
    unsigned short* hb      = (unsigned short*)(ws + 77791232); // 21 MB

    // gate-phase temporaries aliased over the (not-yet-written) W1T/W2T region
    char* G = ws + 10682368;
    unsigned short* hs_hi = (unsigned short*)(G);
    unsigned short* hs_lo = (unsigned short*)(G + 4194304);
    unsigned short* WmT_h = (unsigned short*)(G + 8388608);
    unsigned short* WmT_l = (unsigned short*)(G + 8912896);
    unsigned short* WcT_h = (unsigned short*)(G + 9437184);
    unsigned short* WcT_l = (unsigned short*)(G + 9830400);
    unsigned short* xg_h  = (unsigned short*)(G + 10223616);
    unsigned short* xg_l  = (unsigned short*)(G + 11272192);
    float*          yb    = (float*)(G + 12320768);
    unsigned short* n_h   = (unsigned short*)(G + 14417920);
    unsigned short* n_l   = (unsigned short*)(G + 23855104);
    float*          Zb    = (float*)(G + 33292288);
    float*          Gbuf  = (float*)(G + 52166656);

    k_init<<<1, 256, 0, stream>>>(count, lamb, theta, out, cnt, expg, Gbuf);
    k_split<<<1024, 256, 0, stream>>>(hs, hs_hi, hs_lo);
    k_tsplit<<<dim3(DGc / 32, Dm / 32, 1), 256, 0, stream>>>(Wmlp, WmT_h, WmT_l, Dm, DGc);
    k_tsplit<<<dim3(DGc / 32, DGc / 32, 3), 256, 0, stream>>>(convW, WcT_h, WcT_l, DGc, DGc);
    k_expgA<<<Dm / 64, 256, 0, stream>>>(X, Wst, expg);
    k_gA<<<DGc / 32, 256, 0, stream>>>(expg, convW, Gbuf);
    k_s1fin<<<1, 256, 0, stream>>>(Gbuf, Ahat, S1);
    // xg = silu(hs @ Wmlp) -> hi/lo
    gemm4s<64, Dm, 1><<<dim3(TT / 64, 2), 256, 0, stream>>>(
        hs_hi, hs_lo, WmT_h, WmT_l, nullptr, xg_h, xg_l);
    // y = xg @ convW[0]
    gemm4s<64, DGc, 0><<<dim3(TT / 64, 2), 256, 0, stream>>>(
        xg_h, xg_l, WcT_h, WcT_l, yb, nullptr, nullptr);
    k_l1<<<TT, 256, 0, stream>>>(yb, S1, Ahat, n_h, n_l);
    // layer 2
    gemm4s<128, DGc, 0><<<dim3(TT * Nc / 128, 2), 256, 0, stream>>>(
        n_h, n_l, WcT_h + 65536, WcT_l + 65536, Zb, nullptr, nullptr);
    k_mix2<<<TT, 256, 0, stream>>>(Zb, Ahat, n_h, n_l);
    // layer 3
    gemm4s<128, DGc, 0><<<dim3(TT * Nc / 128, 2), 256, 0, stream>>>(
        n_h, n_l, WcT_h + 131072, WcT_l + 131072, Zb, nullptr, nullptr);
    k_mix3<<<TT / 4, 256, 0, stream>>>(Zb, Ahat, wproj, out, cnt, toklist, wlist);
    // gate temporaries dead; now build FFN weights over that region
    k_tcast<<<dim3(Hc / 32, Dm / 32, Ec), 256, 0, stream>>>(W1, W1T, Dm, Hc);
    k_tcast<<<dim3(Dm / 32, Hc / 32, Ec), 256, 0, stream>>>(W2, W2T, Hc, Dm);
    k_offs<<<1, 1, 0, stream>>>(cnt, poffs, tile_e, tile_m0);
    k_gather<<<PADMAX / 2, 256, 0, stream>>>(hs, cnt, poffs, toklist, wlist,
                                             xb, tokslot, wslot);
    hipMemsetAsync(d_out, 0, (size_t)TT * Dm * sizeof(float), stream);
    k_mfma<Dm, Hc, 0><<<NTILE_MAX * (Hc / 128), 256, 0, stream>>>(
        xb, W1T, tile_e, tile_m0, tokslot, wslot, hb);
    k_mfma<Hc, Dm, 1><<<NTILE_MAX * (Dm / 128), 256, 0, stream>>>(
        hb, W2T, tile_e, tile_m0, tokslot, wslot, out);
}

// Round 7
// 297.510 us; speedup vs baseline: 1.0991x; 1.0991x over previous
//
#include <hip/hip_runtime.h>
#include <math.h>

#define TT 2048   // tokens
#define Dm 1024   // model dim
#define DGc 256   // gate dim
#define Ec 8      // experts
#define Nc 9      // graph nodes
#define Hc 2048   // FFN hidden
#define PADMAX 5120
#define NT64MAX 80   // max 64-row expert tiles

typedef __attribute__((ext_vector_type(8))) short short8v;
typedef __attribute__((ext_vector_type(4))) float f32x4;

typedef __attribute__((address_space(1))) const void gvoid;
typedef __attribute__((address_space(3))) void svoid;

__device__ __forceinline__ void gll16(const void* g, void* l) {
    __builtin_amdgcn_global_load_lds((gvoid*)g, (svoid*)l, 16, 0, 0);
}

__device__ __forceinline__ float silu_f(float x) { return x / (1.f + __expf(-x)); }

__device__ __forceinline__ unsigned short bf16_rne(float f) {
    union { float f; unsigned u; } u; u.f = f;
    return (unsigned short)((u.u + 0x7fffu + ((u.u >> 16) & 1u)) >> 16);
}
__device__ __forceinline__ float bf16_to_f(unsigned short h) {
    union { unsigned u; float f; } u; u.u = ((unsigned)h) << 16; return u.f;
}
__device__ __forceinline__ void split2(float x, unsigned short& h, unsigned short& l) {
    h = bf16_rne(x);
    l = bf16_rne(x - bf16_to_f(h));
}

// ---- init: loss tail, counters, and zero the fp32 split-K accumulators ----
__global__ __launch_bounds__(256) void k_init(const float* count, const float* lamb,
        const float* theta, float* out, int* cnt, float* expg, float* Gbuf,
        float* xgf, float* yb) {
    int gtid = blockIdx.x * 256 + threadIdx.x;
    int tot = gridDim.x * 256;
    if (blockIdx.x == 0 && threadIdx.x < Ec) {
        int i = threadIdx.x;
        float* loss = out + (size_t)TT * Dm;
        loss[(size_t)TT * Ec + i]       = count[i];
        loss[(size_t)(TT + 1) * Ec + i] = lamb[0];
        loss[(size_t)(TT + 2) * Ec + i] = theta[0];
        cnt[i] = 0;
    }
    for (int i = gtid; i < Ec * DGc; i += tot) { expg[i] = 0.f; Gbuf[i] = 0.f; }
    for (int i = gtid; i < TT * DGc / 4; i += tot) {
        ((float4*)xgf)[i] = make_float4(0, 0, 0, 0);
        ((float4*)yb)[i]  = make_float4(0, 0, 0, 0);
    }
}

// ---- split hs fp32 -> hi/lo bf16 (row-major, K-contig) ----
__global__ __launch_bounds__(256) void k_split(const float* src,
        unsigned short* dh, unsigned short* dl) {
    size_t i = ((size_t)blockIdx.x * 256 + threadIdx.x) * 8;
    float4 v0 = *(const float4*)&src[i];
    float4 v1 = *(const float4*)&src[i + 4];
    ushort4 h0, l0, h1, l1;
    split2(v0.x, h0.x, l0.x); split2(v0.y, h0.y, l0.y);
    split2(v0.z, h0.z, l0.z); split2(v0.w, h0.w, l0.w);
    split2(v1.x, h1.x, l1.x); split2(v1.y, h1.y, l1.y);
    split2(v1.z, h1.z, l1.z); split2(v1.w, h1.w, l1.w);
    *(ushort4*)&dh[i] = h0; *(ushort4*)&dh[i + 4] = h1;
    *(ushort4*)&dl[i] = l0; *(ushort4*)&dl[i + 4] = l1;
}

// ---- transpose+split: src[e][R][C] f32 -> dh/dl [e][C][R] bf16 ----
__global__ __launch_bounds__(256) void k_tsplit(const float* src,
        unsigned short* dh, unsigned short* dl, int R, int C) {
    int e = blockIdx.z;
    int c0 = blockIdx.x * 32, r0 = blockIdx.y * 32;
    const float* S = src + (size_t)e * R * C;
    __shared__ float t[32][36];
    int tid = threadIdx.x;
    int i = tid >> 3, j4 = (tid & 7) * 4;
    *(float4*)&t[i][j4] = *(const float4*)&S[(size_t)(r0 + i) * C + c0 + j4];
    __syncthreads();
    int ci = tid >> 3, r4 = (tid & 7) * 4;
    ushort4 h, l;
    split2(t[r4 + 0][ci], h.x, l.x);
    split2(t[r4 + 1][ci], h.y, l.y);
    split2(t[r4 + 2][ci], h.z, l.z);
    split2(t[r4 + 3][ci], h.w, l.w);
    size_t o = (size_t)e * R * C + (size_t)(c0 + ci) * R + r0 + r4;
    *(ushort4*)&dh[o] = h;
    *(ushort4*)&dl[o] = l;
}

// ---- transpose + cast (hi only, FFN weights) ----
__global__ __launch_bounds__(256) void k_tcast(const float* src, unsigned short* dst,
                                               int R, int C) {
    int e = blockIdx.z;
    int c0 = blockIdx.x * 32, r0 = blockIdx.y * 32;
    const float* S = src + (size_t)e * R * C;
    unsigned short* Dq = dst + (size_t)e * R * C;
    __shared__ float t[32][36];
    int tid = threadIdx.x;
    int i = tid >> 3, j4 = (tid & 7) * 4;
    *(float4*)&t[i][j4] = *(const float4*)&S[(size_t)(r0 + i) * C + c0 + j4];
    __syncthreads();
    int ci = tid >> 3, r4 = (tid & 7) * 4;
    ushort4 v;
    v.x = bf16_rne(t[r4 + 0][ci]);
    v.y = bf16_rne(t[r4 + 1][ci]);
    v.z = bf16_rne(t[r4 + 2][ci]);
    v.w = bf16_rne(t[r4 + 3][ci]);
    *(ushort4*)&Dq[(size_t)(c0 + ci) * R + r0 + r4] = v;
}

// ---- expg accumulate (split-K): expg_raw[e][g] += X[e][kb:kb+64] . Wst ----
__global__ __launch_bounds__(256) void k_expgA(const float* X, const float* Wst,
                                               float* expg_raw) {
    int g = threadIdx.x;
    int kb = blockIdx.x * 64;
    __shared__ float xs[Ec][64];
    if (g < 128) {
        int e = g >> 4;
        int k4 = (g & 15) * 4;
        *(float4*)&xs[e][k4] = *(const float4*)&X[(size_t)e * Dm + kb + k4];
    }
    __syncthreads();
    float acc[Ec];
#pragma unroll
    for (int e = 0; e < Ec; e++) acc[e] = 0.f;
#pragma unroll 4
    for (int k = 0; k < 64; k++) {
        float w = Wst[(size_t)(kb + k) * DGc + g];
#pragma unroll
        for (int e = 0; e < Ec; e++) acc[e] += xs[e][k] * w;
    }
#pragma unroll
    for (int e = 0; e < Ec; e++) atomicAdd(&expg_raw[e * DGc + g], acc[e]);
}

// ---- G[m][g] += silu(expg_raw[m])[kb:kb+32] . W0 (split-K, silu folded in) ----
__global__ __launch_bounds__(256) void k_gA(const float* expg_raw, const float* W0,
                                            float* G) {
    int g = threadIdx.x;
    int kb = blockIdx.x * 32;
    __shared__ float xs[Ec][32];
    xs[g >> 5][g & 31] = silu_f(expg_raw[(size_t)(g >> 5) * DGc + kb + (g & 31)]);
    __syncthreads();
    float acc[Ec];
#pragma unroll
    for (int e = 0; e < Ec; e++) acc[e] = 0.f;
#pragma unroll 4
    for (int k = 0; k < 32; k++) {
        float w = W0[(size_t)(kb + k) * DGc + g];
#pragma unroll
        for (int e = 0; e < Ec; e++) acc[e] += xs[e][k] * w;
    }
#pragma unroll
    for (int e = 0; e < Ec; e++) atomicAdd(&G[e * DGc + g], acc[e]);
}

// ---- S1[n] = sum_{m<8} A[n,m] * G[m] ----
__global__ __launch_bounds__(256) void k_s1fin(const float* G, const float* Ahat,
                                               float* S1) {
    int g = threadIdx.x;
    float Gl[Ec];
#pragma unroll
    for (int m = 0; m < Ec; m++) Gl[m] = G[m * DGc + g];
#pragma unroll
    for (int n = 0; n < Nc; n++) {
        float s = 0.f;
#pragma unroll
        for (int m = 0; m < Ec; m++) s += Ahat[n * Nc + m] * Gl[m];
        S1[n * DGc + g] = s;
    }
}

// ---- split-bf16 3-pass MFMA GEMM with optional split-K ----
// EPI 0: write fp32 C (KS=1).  EPI 1: silu + split-write bf16 (KS=1).
// EPI 2: atomicAdd fp32 C (any KS; C must be pre-zeroed).
template<int BM, int KD, int KS, int EPI>
__global__ __launch_bounds__(256) void gemm4s(const unsigned short* Ah,
        const unsigned short* Al, const unsigned short* Bh, const unsigned short* Bl,
        float* Cf, unsigned short* Oh, unsigned short* Ol) {
    constexpr int FM = BM / 32;
    constexpr int AR = BM / 64;
    constexpr int KLEN = KD / KS;
    int m0 = blockIdx.x * BM, n0 = blockIdx.y * 128;
    int k0 = blockIdx.z * KLEN;
    __shared__ __align__(16) unsigned short AsH[BM * 32];
    __shared__ __align__(16) unsigned short AsL[BM * 32];
    __shared__ __align__(16) unsigned short BsH[128 * 32];
    __shared__ __align__(16) unsigned short BsL[128 * 32];
    int tid = threadIdx.x, lane = tid & 63, wid = tid >> 6;
    int wr = wid >> 1, wc = wid & 1, lo = lane & 15, hi = lane >> 4;

    f32x4 acc[FM][4];
#pragma unroll
    for (int m = 0; m < FM; m++)
#pragma unroll
        for (int n = 0; n < 4; n++) acc[m][n] = (f32x4)(0.f);

    int sW = (tid >> 3) & 3;
    size_t aoff = (size_t)(m0 + (tid >> 2)) * KD + ((tid & 3) ^ sW) * 8;
    size_t boff = (size_t)(n0 + (tid >> 2)) * KD + ((tid & 3) ^ sW) * 8;
    int hixor = (hi ^ ((lo >> 1) & 3)) * 8;

    for (int kb = k0; kb < k0 + KLEN; kb += 32) {
#pragma unroll
        for (int r = 0; r < AR; r++) {
            gll16(Ah + aoff + (size_t)r * 64 * KD + kb, (char*)AsH + r * 4096 + tid * 16);
            gll16(Al + aoff + (size_t)r * 64 * KD + kb, (char*)AsL + r * 4096 + tid * 16);
        }
#pragma unroll
        for (int r = 0; r < 2; r++) {
            gll16(Bh + boff + (size_t)r * 64 * KD + kb, (char*)BsH + r * 4096 + tid * 16);
            gll16(Bl + boff + (size_t)r * 64 * KD + kb, (char*)BsL + r * 4096 + tid * 16);
        }
        __syncthreads();
        short8v ah[FM], al[FM], bh[4], bl[4];
#pragma unroll
        for (int m = 0; m < FM; m++) {
            ah[m] = *(const short8v*)&AsH[(wr * (BM / 2) + m * 16 + lo) * 32 + hixor];
            al[m] = *(const short8v*)&AsL[(wr * (BM / 2) + m * 16 + lo) * 32 + hixor];
        }
#pragma unroll
        for (int n = 0; n < 4; n++) {
            bh[n] = *(const short8v*)&BsH[(wc * 64 + n * 16 + lo) * 32 + hixor];
            bl[n] = *(const short8v*)&BsL[(wc * 64 + n * 16 + lo) * 32 + hixor];
        }
#pragma unroll
        for (int m = 0; m < FM; m++)
#pragma unroll
            for (int n = 0; n < 4; n++)
                acc[m][n] = __builtin_amdgcn_mfma_f32_16x16x32_bf16(ah[m], bh[n], acc[m][n], 0, 0, 0);
#pragma unroll
        for (int m = 0; m < FM; m++)
#pragma unroll
            for (int n = 0; n < 4; n++)
                acc[m][n] = __builtin_amdgcn_mfma_f32_16x16x32_bf16(ah[m], bl[n], acc[m][n], 0, 0, 0);
#pragma unroll
        for (int m = 0; m < FM; m++)
#pragma unroll
            for (int n = 0; n < 4; n++)
                acc[m][n] = __builtin_amdgcn_mfma_f32_16x16x32_bf16(al[m], bh[n], acc[m][n], 0, 0, 0);
        __syncthreads();
    }

#pragma unroll
    for (int m = 0; m < FM; m++) {
#pragma unroll
        for (int n = 0; n < 4; n++) {
            int col = n0 + wc * 64 + n * 16 + lo;
#pragma unroll
            for (int r = 0; r < 4; r++) {
                int row = m0 + wr * (BM / 2) + m * 16 + hi * 4 + r;
                if (EPI == 0) {
                    Cf[(size_t)row * 256 + col] = acc[m][n][r];
                } else if (EPI == 2) {
                    atomicAdd(&Cf[(size_t)row * 256 + col], acc[m][n][r]);
                } else {
                    float s = silu_f(acc[m][n][r]);
                    unsigned short h, l;
                    split2(s, h, l);
                    Oh[(size_t)row * 256 + col] = h;
                    Ol[(size_t)row * 256 + col] = l;
                }
            }
        }
    }
}

// ---- silu + split for the xg split-K accumulator ----
__global__ __launch_bounds__(256) void k_finsplit(const float* src,
        unsigned short* dh, unsigned short* dl) {
    size_t i = ((size_t)blockIdx.x * 256 + threadIdx.x) * 4;
    float4 v = *(const float4*)&src[i];
    ushort4 h, l;
    split2(silu_f(v.x), h.x, l.x);
    split2(silu_f(v.y), h.y, l.y);
    split2(silu_f(v.z), h.z, l.z);
    split2(silu_f(v.w), h.w, l.w);
    *(ushort4*)&dh[i] = h;
    *(ushort4*)&dl[i] = l;
}

// ---- layer-1 build: node1[t,n] = silu(S1[n] + A[n,8]*y[t]) -> hi/lo ----
__global__ __launch_bounds__(256) void k_l1(const float* y, const float* S1,
        const float* Ahat, unsigned short* nh, unsigned short* nl) {
    int t = blockIdx.x, g = threadIdx.x;
    float yv = y[(size_t)t * DGc + g];
#pragma unroll
    for (int n = 0; n < Nc; n++) {
        float c = Ahat[n * Nc + Ec];
        float s = silu_f(S1[n * DGc + g] + c * yv);
        unsigned short h, l;
        split2(s, h, l);
        size_t o = ((size_t)t * Nc + n) * DGc + g;
        nh[o] = h; nl[o] = l;
    }
}

// ---- mix: node[t,n] = silu(sum_m A[n,m] Z[t,m]) -> hi/lo ----
__global__ __launch_bounds__(256) void k_mix2(const float* Z, const float* Ahat,
        unsigned short* nh, unsigned short* nl) {
    int t = blockIdx.x, g = threadIdx.x;
    __shared__ float A[Nc * Nc];
    if (g < Nc * Nc) A[g] = Ahat[g];
    __syncthreads();
    float z[Nc];
#pragma unroll
    for (int m = 0; m < Nc; m++) z[m] = Z[((size_t)t * Nc + m) * DGc + g];
#pragma unroll
    for (int n = 0; n < Nc; n++) {
        float s = 0.f;
#pragma unroll
        for (int m = 0; m < Nc; m++) s += A[n * Nc + m] * z[m];
        s = silu_f(s);
        unsigned short h, l;
        split2(s, h, l);
        size_t o = ((size_t)t * Nc + n) * DGc + g;
        nh[o] = h; nl[o] = l;
    }
}

// ---- final mix + logits + softmax + top2 + routing (1 wave per token) ----
__global__ __launch_bounds__(256) void k_mix3(const float* Z, const float* Ahat,
        const float* wproj, float* out, int* cnt, int* toklist, float* wlist) {
    __shared__ float A[Nc * Nc];
    __shared__ float wp[DGc];
    int tid = threadIdx.x;
    if (tid < Nc * Nc) A[tid] = Ahat[tid];
    wp[tid] = wproj[tid];
    __syncthreads();
    int wid = tid >> 6, lane = tid & 63;
    int t = blockIdx.x * 4 + wid;
    float lg[Ec];
#pragma unroll
    for (int e = 0; e < Ec; e++) lg[e] = 0.f;
#pragma unroll
    for (int j = 0; j < 4; j++) {
        int g = j * 64 + lane;
        float z[Nc];
#pragma unroll
        for (int m = 0; m < Nc; m++) z[m] = Z[((size_t)t * Nc + m) * DGc + g];
#pragma unroll
        for (int e = 0; e < Ec; e++) {
            float s = 0.f;
#pragma unroll
            for (int m = 0; m < Nc; m++) s += A[e * Nc + m] * z[m];
            lg[e] += silu_f(s) * wp[g];
        }
    }
#pragma unroll
    for (int off = 32; off >= 1; off >>= 1) {
#pragma unroll
        for (int e = 0; e < Ec; e++) lg[e] += __shfl_xor(lg[e], off);
    }
    if (lane == 0) {
        float mx = -1e30f;
#pragma unroll
        for (int e = 0; e < Ec; e++) mx = fmaxf(mx, lg[e]);
        float pr[Ec], s = 0.f;
#pragma unroll
        for (int e = 0; e < Ec; e++) { pr[e] = __expf(lg[e] - mx); s += pr[e]; }
        float inv = 1.f / s;
        float* lrow = out + (size_t)TT * Dm + (size_t)t * Ec;
#pragma unroll
        for (int e = 0; e < Ec; e++) { pr[e] *= inv; lrow[e] = pr[e]; }
        int i0 = 0; float v0 = pr[0];
#pragma unroll
        for (int e = 1; e < Ec; e++) if (pr[e] > v0) { v0 = pr[e]; i0 = e; }
        int i1 = -1; float v1 = -1e30f;
#pragma unroll
        for (int e = 0; e < Ec; e++) if (e != i0 && pr[e] > v1) { v1 = pr[e]; i1 = e; }
        float* rowT = out + (size_t)TT * Dm + (size_t)TT * Ec;
        atomicAdd(&rowT[i0], 2.f * v0);
        atomicAdd(&rowT[i1], 2.f * v1);
        float winv = 1.f / (v0 + v1);
        int p0 = atomicAdd(&cnt[i0], 1);
        toklist[i0 * TT + p0] = t; wlist[i0 * TT + p0] = v0 * winv;
        int p1 = atomicAdd(&cnt[i1], 1);
        toklist[i1 * TT + p1] = t; wlist[i1 * TT + p1] = v1 * winv;
    }
}

// ---- padded offsets + 64-row tile map ----
__global__ void k_offs(const int* cnt, int* poffs, int* tile_e, int* tile_m0) {
    if (threadIdx.x == 0) {
        int pad = 0, nt = 0;
        for (int e = 0; e < Ec; e++) {
            poffs[e] = pad;
            int te = (cnt[e] + 63) >> 6;
            for (int i = 0; i < te; i++) { tile_e[nt] = e; tile_m0[nt] = pad + i * 64; nt++; }
            pad += te * 64;
        }
        poffs[Ec] = pad;
        for (; nt < NT64MAX; nt++) { tile_e[nt] = -1; tile_m0[nt] = 0; }
    }
}

// ---- gather routed tokens into padded slot-major bf16 buffer + slot maps ----
__global__ __launch_bounds__(256) void k_gather(const float* hs, const int* cnt,
        const int* poffs, const int* toklist, const float* wlist,
        unsigned short* xb, int* tokslot, float* wslot) {
    int tid = threadIdx.x;
    int s = blockIdx.x * 2 + (tid >> 7);
    int j = (tid & 127) * 8;
    int e = 0;
#pragma unroll
    for (int q = 1; q < Ec; q++) if (s >= poffs[q]) e = q;
    int pos = s - poffs[e];
    int tok = -1; float w = 0.f;
    if (pos < cnt[e]) { tok = toklist[e * TT + pos]; w = wlist[e * TT + pos]; }
    if (j == 0) { tokslot[s] = tok; wslot[s] = w; }
    ushort4 o0, o1;
    if (tok >= 0) {
        const float* xr = hs + (size_t)tok * Dm + j;
        o0.x = bf16_rne(xr[0]); o0.y = bf16_rne(xr[1]); o0.z = bf16_rne(xr[2]); o0.w = bf16_rne(xr[3]);
        o1.x = bf16_rne(xr[4]); o1.y = bf16_rne(xr[5]); o1.z = bf16_rne(xr[6]); o1.w = bf16_rne(xr[7]);
    } else {
        o0 = make_ushort4(0, 0, 0, 0); o1 = o0;
    }
    *(ushort4*)&xb[(size_t)s * Dm + j] = o0;
    *(ushort4*)&xb[(size_t)s * Dm + j + 4] = o1;
}

// ---- FFN MFMA grouped GEMM: 64x128 tiles, optional split-K, XCD remap ----
template<int KDIM, int NDIM, int MODE, int KS>
__global__ __launch_bounds__(256) void k_mfma(const unsigned short* Abuf,
        const unsigned short* Wt, const int* tile_e, const int* tile_m0,
        const int* tokslot, const float* wslot, void* outp) {
    constexpr int NY = NDIM / 128;
    constexpr int KLEN = KDIM / KS;
    constexpr int CPX = (NT64MAX * NY * KS) / 8;
    int bid = blockIdx.x;
    int flat = (bid & 7) * CPX + (bid >> 3);
    int tx = flat / (NY * KS);
    int rem = flat % (NY * KS);
    int y = rem / KS, ks = rem % KS;
    int e = tile_e[tx];
    if (e < 0) return;
    int m0 = tile_m0[tx];
    int n0 = y * 128;
    int k0 = ks * KLEN;
    __shared__ __align__(16) unsigned short As[64 * 32];    // 4 KB
    __shared__ __align__(16) unsigned short Bs[128 * 32];   // 8 KB
    int tid = threadIdx.x;
    int lane = tid & 63;
    int wid = tid >> 6;
    int wr = wid >> 1, wc = wid & 1;
    int lo = lane & 15, hi = lane >> 4;

    f32x4 acc[2][4];
#pragma unroll
    for (int m = 0; m < 2; m++)
#pragma unroll
        for (int n = 0; n < 4; n++) acc[m][n] = (f32x4)(0.f);

    int arow = tid >> 2;
    int sW = (tid >> 3) & 3;
    int acol = ((tid & 3) ^ sW) * 8;           // pre-swizzled source col-block
    int hixor = (hi ^ ((lo >> 1) & 3)) * 8;    // swizzled read offset
    const unsigned short* Ag = Abuf + (size_t)m0 * KDIM;
    const unsigned short* Bt = Wt + (size_t)e * NDIM * KDIM + (size_t)n0 * KDIM;

    for (int kb = k0; kb < k0 + KLEN; kb += 32) {
        gll16(Ag + (size_t)arow * KDIM + kb + acol,        (char*)As + tid * 16);
        gll16(Bt + (size_t)arow * KDIM + kb + acol,        (char*)Bs + tid * 16);
        gll16(Bt + (size_t)(arow + 64) * KDIM + kb + acol, (char*)Bs + 4096 + tid * 16);
        __syncthreads();
        short8v a[2], b[4];
#pragma unroll
        for (int m = 0; m < 2; m++)
            a[m] = *(const short8v*)&As[(wr * 32 + m * 16 + lo) * 32 + hixor];
#pragma unroll
        for (int n = 0; n < 4; n++)
            b[n] = *(const short8v*)&Bs[(wc * 64 + n * 16 + lo) * 32 + hixor];
#pragma unroll
        for (int m = 0; m < 2; m++)
#pragma unroll
            for (int n = 0; n < 4; n++)
                acc[m][n] = __builtin_amdgcn_mfma_f32_16x16x32_bf16(a[m], b[n], acc[m][n], 0, 0, 0);
        __syncthreads();
    }

    if (MODE == 0) {
        unsigned short* O = (unsigned short*)outp;
#pragma unroll
        for (int m = 0; m < 2; m++) {
#pragma unroll
            for (int n = 0; n < 4; n++) {
                int col = n0 + wc * 64 + n * 16 + lo;
#pragma unroll
                for (int r = 0; r < 4; r++) {
                    int row = m0 + wr * 32 + m * 16 + hi * 4 + r;
                    O[(size_t)row * NDIM + col] = bf16_rne(silu_f(acc[m][n][r]));
                }
            }
        }
    } else {
        float* O = (float*)outp;
#pragma unroll
        for (int m = 0; m < 2; m++) {
            int toks[4]; float ws[4];
#pragma unroll
            for (int r = 0; r < 4; r++) {
                int row = m0 + wr * 32 + m * 16 + hi * 4 + r;
                toks[r] = tokslot[row];
                ws[r] = wslot[row];
            }
#pragma unroll
            for (int n = 0; n < 4; n++) {
                int col = n0 + wc * 64 + n * 16 + lo;
#pragma unroll
                for (int r = 0; r < 4; r++) {
                    if (toks[r] >= 0)
                        atomicAdd(&O[(size_t)toks[r] * Dm + col], ws[r] * acc[m][n][r]);
                }
            }
        }
    }
}

extern "C" void kernel_launch(void* const* d_in, const int* in_sizes, int n_in,
                              void* d_out, int out_size, void* d_ws, size_t ws_size,
                              hipStream_t stream) {
    const float* hs    = (const float*)d_in[0];
    const float* X     = (const float*)d_in[1];
    const float* Wmlp  = (const float*)d_in[2];
    const float* Wst   = (const float*)d_in[3];
    const float* convW = (const float*)d_in[4];
    const float* wproj = (const float*)d_in[5];
    const float* W1    = (const float*)d_in[6];
    const float* W2    = (const float*)d_in[7];
    const float* lamb  = (const float*)d_in[8];
    const float* theta = (const float*)d_in[9];
    const float* count = (const float*)d_in[10];
    const float* Ahat  = (const float*)d_in[11];
    float* out = (float*)d_out;
    char* ws = (char*)d_ws;

    // persistent layout
    float*          expg    = (float*)ws;                       // raw accum (silu on read)
    int*            cnt     = (int*)(ws + 8192);
    int*            poffs   = (int*)(ws + 8320);
    int*            tile_e  = (int*)(ws + 8448);                // 80 ints
    int*            tile_m0 = (int*)(ws + 8960);                // 80 ints
    float*          S1      = (float*)(ws + 9472);
    int*            toklist = (int*)(ws + 20480);
    float*          wlist   = (float*)(ws + 86016);
    int*            tokslot = (int*)(ws + 151552);
    float*          wslot   = (float*)(ws + 172032);
    unsigned short* xb      = (unsigned short*)(ws + 196608);   // 10.5 MB
    unsigned short* W1T     = (unsigned short*)(ws + 10682368); // 33.5 MB
    unsigned short* W2T     = (unsigned short*)(ws + 44236800); // 33.5 MB
    unsigned short* hb      = (unsigned short*)(ws + 77791232); // 21 MB

    // gate-phase temporaries aliased over the (not-yet-written) W1T/W2T region
    char* G = ws + 10682368;
    unsigned short* hs_hi = (unsigned short*)(G);
    unsigned short* hs_lo = (unsigned short*)(G + 4194304);
    unsigned short* WmT_h = (unsigned short*)(G + 8388608);
    unsigned short* WmT_l = (unsigned short*)(G + 8912896);
    unsigned short* WcT_h = (unsigned short*)(G + 9437184);
    unsigned short* WcT_l = (unsigned short*)(G + 9830400);
    unsigned short* xg_h  = (unsigned short*)(G + 10223616);
    unsigned short* xg_l  = (unsigned short*)(G + 11272192);
    float*          yb    = (float*)(G + 12320768);             // 2 MB f32
    unsigned short* n_h   = (unsigned short*)(G + 14417920);
    unsigned short* n_l   = (unsigned short*)(G + 23855104);
    float*          Zb    = (float*)(G + 33292288);
    float*          Gbuf  = (float*)(G + 52166656);             // 8 KB
    float*          xgf   = (float*)(G + 52183040);             // 2 MB f32

    k_init<<<64, 256, 0, stream>>>(count, lamb, theta, out, cnt, expg, Gbuf, xgf, yb);
    k_split<<<1024, 256, 0, stream>>>(hs, hs_hi, hs_lo);
    k_tsplit<<<dim3(DGc / 32, Dm / 32, 1), 256, 0, stream>>>(Wmlp, WmT_h, WmT_l, Dm, DGc);
    k_tsplit<<<dim3(DGc / 32, DGc / 32, 3), 256, 0, stream>>>(convW, WcT_h, WcT_l, DGc, DGc);
    k_expgA<<<Dm / 64, 256, 0, stream>>>(X, Wst, expg);
    k_gA<<<DGc / 32, 256, 0, stream>>>(expg, convW, Gbuf);
    k_s1fin<<<1, 256, 0, stream>>>(Gbuf, Ahat, S1);
    // xg = silu(hs @ Wmlp): split-K=4 atomic accumulate, then silu+split
    gemm4s<64, Dm, 4, 2><<<dim3(TT / 64, 2, 4), 256, 0, stream>>>(
        hs_hi, hs_lo, WmT_h, WmT_l, xgf, nullptr, nullptr);
    k_finsplit<<<TT * DGc / 1024, 256, 0, stream>>>(xgf, xg_h, xg_l);
    // y = xg @ convW[0]: split-K=2 atomic accumulate into yb
    gemm4s<64, DGc, 2, 2><<<dim3(TT / 64, 2, 2), 256, 0, stream>>>(
        xg_h, xg_l, WcT_h, WcT_l, yb, nullptr, nullptr);
    k_l1<<<TT, 256, 0, stream>>>(yb, S1, Ahat, n_h, n_l);
    // layer 2
    gemm4s<64, DGc, 1, 0><<<dim3(TT * Nc / 64, 2, 1), 256, 0, stream>>>(
        n_h, n_l, WcT_h + 65536, WcT_l + 65536, Zb, nullptr, nullptr);
    k_mix2<<<TT, 256, 0, stream>>>(Zb, Ahat, n_h, n_l);
    // layer 3
    gemm4s<64, DGc, 1, 0><<<dim3(TT * Nc / 64, 2, 1), 256, 0, stream>>>(
        n_h, n_l, WcT_h + 131072, WcT_l + 131072, Zb, nullptr, nullptr);
    k_mix3<<<TT / 4, 256, 0, stream>>>(Zb, Ahat, wproj, out, cnt, toklist, wlist);
    // gate temporaries dead; now build FFN weights over that region
    k_tcast<<<dim3(Hc / 32, Dm / 32, Ec), 256, 0, stream>>>(W1, W1T, Dm, Hc);
    k_tcast<<<dim3(Dm / 32, Hc / 32, Ec), 256, 0, stream>>>(W2, W2T, Hc, Dm);
    k_offs<<<1, 1, 0, stream>>>(cnt, poffs, tile_e, tile_m0);
    k_gather<<<PADMAX / 2, 256, 0, stream>>>(hs, cnt, poffs, toklist, wlist,
                                             xb, tokslot, wslot);
    hipMemsetAsync(d_out, 0, (size_t)TT * Dm * sizeof(float), stream);
    k_mfma<Dm, Hc, 0, 1><<<NT64MAX * (Hc / 128), 256, 0, stream>>>(
        xb, W1T, tile_e, tile_m0, tokslot, wslot, hb);
    k_mfma<Hc, Dm, 1, 2><<<NT64MAX * (Dm / 128) * 2, 256, 0, stream>>>(
        hb, W2T, tile_e, tile_m0, tokslot, wslot, out);
}